// Round 1
// baseline (327.217 us; speedup 1.0000x reference)
//
#include <hip/hip_runtime.h>
#include <math.h>

// FeatGuide_BatchDrop: b=32, c=256, h=w=64, r_se=16, r_dy=4, K=2
// LAMBDAS={1,1,.5,.5}, INIT_V={1,0,0,0}, rh=int(.05*64)=3, rw=int(.1*64)=6
// sx=min(ceil(64*sig),61), sy=min(ceil(64*sig),58)

#define BATCH 32
#define CH 256
#define HW 64
#define PLANE (HW * HW)          // 4096
#define NPLANES (BATCH * CH)     // 8192

__device__ __forceinline__ float sigf(float x) { return 1.0f / (1.0f + expf(-x)); }

// ---------------------------------------------------------------------------
// Kernel T: transpose the 6 weight matrices so GEMV inner loops are coalesced.
// ch_w/cw_w: (256,256) -> [in][out]; dh/dw_fc1w: (64,256) -> [in(256)][out(64)];
// dh/dw_fc2w: (1024,64) -> [in(64)][out(1024)]
// ---------------------------------------------------------------------------
__global__ __launch_bounds__(256) void transpose_weights(
    const float* __restrict__ ch_w, const float* __restrict__ cw_w,
    const float* __restrict__ dh1,  const float* __restrict__ dw1,
    const float* __restrict__ dh2,  const float* __restrict__ dw2,
    float* __restrict__ chT, float* __restrict__ cwT,
    float* __restrict__ dh1T, float* __restrict__ dw1T,
    float* __restrict__ dh2T, float* __restrict__ dw2T)
{
    int idx = blockIdx.x * 256 + threadIdx.x;
    if (idx < 65536) {                    // ch_w 256x256
        int r = idx >> 8, c = idx & 255;
        chT[c * 256 + r] = ch_w[idx];
    } else if (idx < 131072) {            // cw_w 256x256
        int i = idx - 65536; int r = i >> 8, c = i & 255;
        cwT[c * 256 + r] = cw_w[i];
    } else if (idx < 147456) {            // dh_fc1w 64x256
        int i = idx - 131072; int r = i >> 8, c = i & 255;
        dh1T[c * 64 + r] = dh1[i];
    } else if (idx < 163840) {            // dw_fc1w 64x256
        int i = idx - 147456; int r = i >> 8, c = i & 255;
        dw1T[c * 64 + r] = dw1[i];
    } else if (idx < 229376) {            // dh_fc2w 1024x64
        int i = idx - 163840; int r = i >> 6, c = i & 63;
        dh2T[c * 1024 + r] = dh2[i];
    } else if (idx < 294912) {            // dw_fc2w 1024x64
        int i = idx - 229376; int r = i >> 6, c = i & 63;
        dw2T[c * 1024 + r] = dw2[i];
    }
}

// ---------------------------------------------------------------------------
// Kernel A: per-(b,c) mean over the 64x64 plane. One wave per plane.
// ---------------------------------------------------------------------------
__global__ __launch_bounds__(256) void mean_kernel(const float* __restrict__ x,
                                                   float* __restrict__ mean)
{
    int wid = threadIdx.x >> 6, lane = threadIdx.x & 63;
    int p = blockIdx.x * 4 + wid;                 // 2048 blocks * 4 waves = 8192
    const float4* xp = (const float4*)(x + (size_t)p * PLANE);
    float s = 0.f;
#pragma unroll
    for (int k = 0; k < 16; ++k) {
        float4 v = xp[lane + 64 * k];
        s += (v.x + v.y) + (v.z + v.w);
    }
#pragma unroll
    for (int off = 32; off; off >>= 1) s += __shfl_xor(s, off, 64);
    if (lane == 0) mean[p] = s * (1.f / 4096.f);
}

// ---------------------------------------------------------------------------
// Kernel B: SE MLP + both dyrelu chains -> scale (y), sx, sy per (b,c).
// One block per batch element; thread t owns channel t.
// All GEMVs use transposed weights: coalesced column loads + LDS broadcast.
// ---------------------------------------------------------------------------
__global__ __launch_bounds__(256) void mlp_kernel(
    const float* __restrict__ mean,
    const float* __restrict__ se_w1, const float* __restrict__ se_w2,
    const float* __restrict__ ch_b,  const float* __restrict__ cw_b,
    const float* __restrict__ dh1b,  const float* __restrict__ dh2b,
    const float* __restrict__ dw1b,  const float* __restrict__ dw2b,
    const float* __restrict__ chT,   const float* __restrict__ cwT,
    const float* __restrict__ dh1T,  const float* __restrict__ dw1T,
    const float* __restrict__ dh2T,  const float* __restrict__ dw2T,
    float* __restrict__ scale, int* __restrict__ sx, int* __restrict__ sy)
{
    __shared__ float m_sh[256], t1_sh[16], g_sh[256], vh_sh[256], vw_sh[256];
    __shared__ float th1h_sh[64], th1w_sh[64], th2h_sh[1024], th2w_sh[1024];

    int b = blockIdx.x, t = threadIdx.x;
    m_sh[t] = mean[b * 256 + t];
    __syncthreads();

    // SE fc1: 16 outputs, dot-256 (tiny; serial threads, LDS broadcasts)
    if (t < 16) {
        float s = 0.f;
        for (int c = 0; c < 256; ++c) s = fmaf(m_sh[c], se_w1[t * 256 + c], s);
        t1_sh[t] = fmaxf(s, 0.f);
    }
    __syncthreads();

    // SE fc2 + sigmoid -> y; g = m*y
    float acc = 0.f;
#pragma unroll
    for (int j = 0; j < 16; ++j) acc = fmaf(t1_sh[j], se_w2[t * 16 + j], acc);
    float y = sigf(acc);
    float g = m_sh[t] * y;
    g_sh[t] = g;
    scale[b * 256 + t] = y;
    __syncthreads();

    // vh = ch_w @ g + ch_b ; vw = cw_w @ g + cw_b  (coalesced via chT/cwT)
    float vh = ch_b[t], vw = cw_b[t];
#pragma unroll 4
    for (int j = 0; j < 256; ++j) {
        float gj = g_sh[j];
        vh = fmaf(gj, chT[j * 256 + t], vh);
        vw = fmaf(gj, cwT[j * 256 + t], vw);
    }
    vh_sh[t] = vh; vw_sh[t] = vw;
    __syncthreads();

    // dyrelu fc1 (64 outputs each branch); wave0 -> h, wave1 -> w
    if (t < 64) {
        float s = dh1b[t];
#pragma unroll 4
        for (int c = 0; c < 256; ++c) s = fmaf(vh_sh[c], dh1T[c * 64 + t], s);
        th1h_sh[t] = fmaxf(s, 0.f);
    } else if (t < 128) {
        int r = t - 64;
        float s = dw1b[r];
#pragma unroll 4
        for (int c = 0; c < 256; ++c) s = fmaf(vw_sh[c], dw1T[c * 64 + r], s);
        th1w_sh[r] = fmaxf(s, 0.f);
    }
    __syncthreads();

    // dyrelu fc2: 1024 outputs per branch; thread t owns rows t, t+256, t+512, t+768
    float ah0 = 0, ah1 = 0, ah2 = 0, ah3 = 0;
    float aw0 = 0, aw1 = 0, aw2 = 0, aw3 = 0;
#pragma unroll 4
    for (int j = 0; j < 64; ++j) {
        float sh = th1h_sh[j], sw = th1w_sh[j];
        const float* ph = dh2T + j * 1024 + t;
        const float* pw = dw2T + j * 1024 + t;
        ah0 = fmaf(sh, ph[0], ah0);   ah1 = fmaf(sh, ph[256], ah1);
        ah2 = fmaf(sh, ph[512], ah2); ah3 = fmaf(sh, ph[768], ah3);
        aw0 = fmaf(sw, pw[0], aw0);   aw1 = fmaf(sw, pw[256], aw1);
        aw2 = fmaf(sw, pw[512], aw2); aw3 = fmaf(sw, pw[768], aw3);
    }
    th2h_sh[t      ] = ah0 + dh2b[t      ];
    th2h_sh[t + 256] = ah1 + dh2b[t + 256];
    th2h_sh[t + 512] = ah2 + dh2b[t + 512];
    th2h_sh[t + 768] = ah3 + dh2b[t + 768];
    th2w_sh[t      ] = aw0 + dw2b[t      ];
    th2w_sh[t + 256] = aw1 + dw2b[t + 256];
    th2w_sh[t + 512] = aw2 + dw2b[t + 512];
    th2w_sh[t + 768] = aw3 + dw2b[t + 768];
    __syncthreads();

    // finalize channel t: coefs = (2*sig(theta)-1)*LAMBDA + INIT; u = max(v*a+b)
    const float LAM[4] = {1.f, 1.f, 0.5f, 0.5f};
    const float INI[4] = {1.f, 0.f, 0.f, 0.f};
    float coh[4], cow[4];
#pragma unroll
    for (int i = 0; i < 4; ++i) {
        float thh = 2.f * sigf(th2h_sh[t * 4 + i]) - 1.f;
        float thw = 2.f * sigf(th2w_sh[t * 4 + i]) - 1.f;
        coh[i] = thh * LAM[i] + INI[i];
        cow[i] = thw * LAM[i] + INI[i];
    }
    float uh = fmaxf(vh * coh[0] + coh[2], vh * coh[1] + coh[3]);
    float uw = fmaxf(vw * cow[0] + cow[2], vw * cow[1] + cow[3]);
    float sxf = fminf(ceilf(64.f * sigf(uh)), 61.f);   // h - rh = 61
    float syf = fminf(ceilf(64.f * sigf(uw)), 58.f);   // w - rw = 58
    sx[b * 256 + t] = (int)sxf;
    sy[b * 256 + t] = (int)syf;
}

// ---------------------------------------------------------------------------
// Kernel C: out = x * y[b,c], zeroing the rh(3) x rw(6) rectangle.
// One block per plane; 256 threads x 4 float4 each = 4096 elems.
// ---------------------------------------------------------------------------
__global__ __launch_bounds__(256) void apply_kernel(
    const float* __restrict__ x, const float* __restrict__ scale,
    const int* __restrict__ sx, const int* __restrict__ sy,
    float* __restrict__ out)
{
    int p = blockIdx.x;
    float s = scale[p];
    int rx = sx[p], cy = sy[p];
    const float4* xp = (const float4*)(x + (size_t)p * PLANE);
    float4* op = (float4*)(out + (size_t)p * PLANE);
    int t = threadIdx.x;
#pragma unroll
    for (int q = 0; q < 4; ++q) {
        int i4 = t + 256 * q;
        float4 v = xp[i4];
        int row = i4 >> 4;              // (i4*4)/64
        int col0 = (i4 & 15) * 4;
        bool rin = (row >= rx) && (row < rx + 3);
        float4 o;
        o.x = (rin && col0     >= cy && col0     < cy + 6) ? 0.f : v.x * s;
        o.y = (rin && col0 + 1 >= cy && col0 + 1 < cy + 6) ? 0.f : v.y * s;
        o.z = (rin && col0 + 2 >= cy && col0 + 2 < cy + 6) ? 0.f : v.z * s;
        o.w = (rin && col0 + 3 >= cy && col0 + 3 < cy + 6) ? 0.f : v.w * s;
        op[i4] = o;
    }
}

// ---------------------------------------------------------------------------
extern "C" void kernel_launch(void* const* d_in, const int* in_sizes, int n_in,
                              void* d_out, int out_size, void* d_ws, size_t ws_size,
                              hipStream_t stream)
{
    const float* x      = (const float*)d_in[0];
    const float* se_w1  = (const float*)d_in[1];
    const float* se_w2  = (const float*)d_in[2];
    const float* ch_w   = (const float*)d_in[3];
    const float* ch_b   = (const float*)d_in[4];
    const float* cw_w   = (const float*)d_in[5];
    const float* cw_b   = (const float*)d_in[6];
    const float* dh1w   = (const float*)d_in[7];
    const float* dh1b   = (const float*)d_in[8];
    const float* dh2w   = (const float*)d_in[9];
    const float* dh2b   = (const float*)d_in[10];
    const float* dw1w   = (const float*)d_in[11];
    const float* dw1b   = (const float*)d_in[12];
    const float* dw2w   = (const float*)d_in[13];
    const float* dw2b   = (const float*)d_in[14];
    float* out = (float*)d_out;

    // workspace layout (floats)
    float* ws    = (float*)d_ws;
    float* meanb = ws;                    // 8192
    float* scale = ws + 8192;             // 8192
    int*   sxp   = (int*)(ws + 16384);    // 8192
    int*   syp   = (int*)(ws + 24576);    // 8192
    float* chT   = ws + 32768;            // 65536
    float* cwT   = chT + 65536;           // 65536
    float* dh1T  = cwT + 65536;           // 16384
    float* dw1T  = dh1T + 16384;          // 16384
    float* dh2T  = dw1T + 16384;          // 65536
    float* dw2T  = dh2T + 65536;          // 65536  (total ~1.31 MB)

    transpose_weights<<<1152, 256, 0, stream>>>(ch_w, cw_w, dh1w, dw1w, dh2w, dw2w,
                                                chT, cwT, dh1T, dw1T, dh2T, dw2T);
    mean_kernel<<<NPLANES / 4, 256, 0, stream>>>(x, meanb);
    mlp_kernel<<<BATCH, 256, 0, stream>>>(meanb, se_w1, se_w2, ch_b, cw_b,
                                          dh1b, dh2b, dw1b, dw2b,
                                          chT, cwT, dh1T, dw1T, dh2T, dw2T,
                                          scale, sxp, syp);
    apply_kernel<<<NPLANES, 256, 0, stream>>>(x, scale, sxp, syp, out);
}

// Round 3
// 298.499 us; speedup vs baseline: 1.0962x; 1.0962x over previous
//
#include <hip/hip_runtime.h>
#include <math.h>

// FeatGuide_BatchDrop: b=32, c=256, h=w=64, r_se=16, r_dy=4, K=2
// LAMBDAS={1,1,.5,.5}, INIT_V={1,0,0,0}, rh=3, rw=6
// sx=min(ceil(64*sig),61), sy=min(ceil(64*sig),58)

#define BATCH 32
#define CH 256
#define HW 64
#define PLANE (HW * HW)          // 4096
#define NPLANES (BATCH * CH)     // 8192

typedef float vf4 __attribute__((ext_vector_type(4)));

__device__ __forceinline__ float sigf(float x) { return 1.0f / (1.0f + expf(-x)); }

// ---------------------------------------------------------------------------
// Kernel T: transpose the 6 weight matrices so GEMV inner loops are coalesced.
// ---------------------------------------------------------------------------
__global__ __launch_bounds__(256) void transpose_weights(
    const float* __restrict__ ch_w, const float* __restrict__ cw_w,
    const float* __restrict__ dh1,  const float* __restrict__ dw1,
    const float* __restrict__ dh2,  const float* __restrict__ dw2,
    float* __restrict__ chT, float* __restrict__ cwT,
    float* __restrict__ dh1T, float* __restrict__ dw1T,
    float* __restrict__ dh2T, float* __restrict__ dw2T)
{
    int idx = blockIdx.x * 256 + threadIdx.x;
    if (idx < 65536) {                    // ch_w 256x256
        int r = idx >> 8, c = idx & 255;
        chT[c * 256 + r] = ch_w[idx];
    } else if (idx < 131072) {            // cw_w 256x256
        int i = idx - 65536; int r = i >> 8, c = i & 255;
        cwT[c * 256 + r] = cw_w[i];
    } else if (idx < 147456) {            // dh_fc1w 64x256
        int i = idx - 131072; int r = i >> 8, c = i & 255;
        dh1T[c * 64 + r] = dh1[i];
    } else if (idx < 163840) {            // dw_fc1w 64x256
        int i = idx - 147456; int r = i >> 8, c = i & 255;
        dw1T[c * 64 + r] = dw1[i];
    } else if (idx < 229376) {            // dh_fc2w 1024x64
        int i = idx - 163840; int r = i >> 6, c = i & 63;
        dh2T[c * 1024 + r] = dh2[i];
    } else if (idx < 294912) {            // dw_fc2w 1024x64
        int i = idx - 229376; int r = i >> 6, c = i & 63;
        dw2T[c * 1024 + r] = dw2[i];
    }
}

// ---------------------------------------------------------------------------
// Kernel A: per-(b,c) mean over the 64x64 plane. One wave per plane.
// ---------------------------------------------------------------------------
__global__ __launch_bounds__(256) void mean_kernel(const float* __restrict__ x,
                                                   float* __restrict__ mean)
{
    int wid = threadIdx.x >> 6, lane = threadIdx.x & 63;
    int p = blockIdx.x * 4 + wid;                 // 2048 blocks * 4 waves = 8192
    const vf4* xp = (const vf4*)(x + (size_t)p * PLANE);
    float s0 = 0.f, s1 = 0.f;
#pragma unroll
    for (int k = 0; k < 16; k += 2) {
        vf4 v0 = xp[lane + 64 * k];
        vf4 v1 = xp[lane + 64 * (k + 1)];
        s0 += (v0.x + v0.y) + (v0.z + v0.w);
        s1 += (v1.x + v1.y) + (v1.z + v1.w);
    }
    float s = s0 + s1;
#pragma unroll
    for (int off = 32; off; off >>= 1) s += __shfl_xor(s, off, 64);
    if (lane == 0) mean[p] = s * (1.f / 4096.f);
}

// ---------------------------------------------------------------------------
// Kernel B: one block per (batch, branch). Each block recomputes the tiny SE
// for its batch (redundant across the 2 branch blocks — cheaper than a launch),
// then runs its dyrelu chain. branch 0 = h (sx), 1 = w (sy).
// ---------------------------------------------------------------------------
__global__ __launch_bounds__(256) void mlp_kernel(
    const float* __restrict__ mean,
    const float* __restrict__ se_w1, const float* __restrict__ se_w2,
    const float* __restrict__ ch_b,  const float* __restrict__ cw_b,
    const float* __restrict__ dh1b,  const float* __restrict__ dw1b,
    const float* __restrict__ dh2b,  const float* __restrict__ dw2b,
    const float* __restrict__ chT,   const float* __restrict__ cwT,
    const float* __restrict__ dh1T,  const float* __restrict__ dw1T,
    const float* __restrict__ dh2T,  const float* __restrict__ dw2T,
    float* __restrict__ scale, int* __restrict__ sx, int* __restrict__ sy)
{
    __shared__ float m_sh[256], part_sh[16][17], t1_sh[16];
    __shared__ float g_sh[256], v_sh[256], red_sh[4][64];
    __shared__ float th1_sh[64], th2_sh[1024];

    int b = blockIdx.x >> 1, br = blockIdx.x & 1;
    const float* cT  = br ? cwT  : chT;
    const float* cb  = br ? cw_b : ch_b;
    const float* f1T = br ? dw1T : dh1T;
    const float* f1b = br ? dw1b : dh1b;
    const float* f2T = br ? dw2T : dh2T;
    const float* f2b = br ? dw2b : dh2b;
    int*  so  = br ? sy : sx;
    float lim = br ? 58.f : 61.f;

    int t = threadIdx.x;
    m_sh[t] = mean[b * 256 + t];
    __syncthreads();

    // --- SE fc1: output o = t&15, partial part = t>>4 over 16 elements ---
    {
        int o = t & 15, part = t >> 4;
        const float* w = se_w1 + o * 256 + part * 16;
        const float* mm = m_sh + part * 16;
        float s = 0.f;
#pragma unroll
        for (int j = 0; j < 16; ++j) s = fmaf(mm[j], w[j], s);
        part_sh[o][part] = s;
    }
    __syncthreads();
    if (t < 16) {
        float a = 0.f;
#pragma unroll
        for (int p = 0; p < 16; ++p) a += part_sh[t][p];
        t1_sh[t] = fmaxf(a, 0.f);
    }
    __syncthreads();

    // --- SE fc2 + sigmoid; g = m*y ---
    {
        float acc = 0.f;
#pragma unroll
        for (int j = 0; j < 16; ++j) acc = fmaf(t1_sh[j], se_w2[t * 16 + j], acc);
        float y = sigf(acc);
        g_sh[t] = m_sh[t] * y;
        if (br == 0) scale[b * 256 + t] = y;
    }
    __syncthreads();

    // --- v = cT^T @ g + cb (coalesced column loads, g broadcast from LDS) ---
    float v = cb[t];
#pragma unroll 8
    for (int j = 0; j < 256; ++j) v = fmaf(g_sh[j], cT[j * 256 + t], v);
    v_sh[t] = v;
    __syncthreads();

    // --- dyrelu fc1: 64 outputs; 4 partials of 64 elems each ---
    {
        int o = t & 63, part = t >> 6;
        const float* vs = v_sh + part * 64;
        float s = 0.f;
#pragma unroll 8
        for (int j = 0; j < 64; ++j) s = fmaf(vs[j], f1T[(part * 64 + j) * 64 + o], s);
        red_sh[part][o] = s;
    }
    __syncthreads();
    if (t < 64)
        th1_sh[t] = fmaxf(red_sh[0][t] + red_sh[1][t] + red_sh[2][t] + red_sh[3][t] + f1b[t], 0.f);
    __syncthreads();

    // --- dyrelu fc2: 1024 outputs; thread t owns t, t+256, t+512, t+768 ---
    float a0 = 0, a1 = 0, a2 = 0, a3 = 0;
#pragma unroll 8
    for (int j = 0; j < 64; ++j) {
        float s1 = th1_sh[j];
        const float* p = f2T + j * 1024 + t;
        a0 = fmaf(s1, p[0],   a0);
        a1 = fmaf(s1, p[256], a1);
        a2 = fmaf(s1, p[512], a2);
        a3 = fmaf(s1, p[768], a3);
    }
    th2_sh[t      ] = a0 + f2b[t      ];
    th2_sh[t + 256] = a1 + f2b[t + 256];
    th2_sh[t + 512] = a2 + f2b[t + 512];
    th2_sh[t + 768] = a3 + f2b[t + 768];
    __syncthreads();

    // --- finalize channel t ---
    const float LAM[4] = {1.f, 1.f, 0.5f, 0.5f};
    const float INI[4] = {1.f, 0.f, 0.f, 0.f};
    float co[4];
#pragma unroll
    for (int i = 0; i < 4; ++i) {
        float th = 2.f * sigf(th2_sh[t * 4 + i]) - 1.f;
        co[i] = th * LAM[i] + INI[i];
    }
    float u = fmaxf(v * co[0] + co[2], v * co[1] + co[3]);
    so[b * 256 + t] = (int)fminf(ceilf(64.f * sigf(u)), lim);
}

// ---------------------------------------------------------------------------
// Kernel C: out = x * y[b,c], zeroing the 3x6 rectangle. Plain stores
// (nontemporal stores caused post-timing divergence vs the poison fills — R2).
// ---------------------------------------------------------------------------
__global__ __launch_bounds__(256) void apply_kernel(
    const float* __restrict__ x, const float* __restrict__ scale,
    const int* __restrict__ sx, const int* __restrict__ sy,
    float* __restrict__ out)
{
    int p = blockIdx.x;
    float s = scale[p];
    int rx = sx[p], cy = sy[p];
    const vf4* xp = (const vf4*)(x + (size_t)p * PLANE);
    vf4* op = (vf4*)(out + (size_t)p * PLANE);
    int t = threadIdx.x;
#pragma unroll
    for (int q = 0; q < 4; ++q) {
        int i4 = t + 256 * q;
        vf4 v = xp[i4];
        int row = i4 >> 4;              // (i4*4)/64
        int col0 = (i4 & 15) * 4;
        bool rin = (row >= rx) && (row < rx + 3);
        vf4 o;
        o.x = (rin && col0     >= cy && col0     < cy + 6) ? 0.f : v.x * s;
        o.y = (rin && col0 + 1 >= cy && col0 + 1 < cy + 6) ? 0.f : v.y * s;
        o.z = (rin && col0 + 2 >= cy && col0 + 2 < cy + 6) ? 0.f : v.z * s;
        o.w = (rin && col0 + 3 >= cy && col0 + 3 < cy + 6) ? 0.f : v.w * s;
        op[i4] = o;
    }
}

// ---------------------------------------------------------------------------
extern "C" void kernel_launch(void* const* d_in, const int* in_sizes, int n_in,
                              void* d_out, int out_size, void* d_ws, size_t ws_size,
                              hipStream_t stream)
{
    const float* x      = (const float*)d_in[0];
    const float* se_w1  = (const float*)d_in[1];
    const float* se_w2  = (const float*)d_in[2];
    const float* ch_w   = (const float*)d_in[3];
    const float* ch_b   = (const float*)d_in[4];
    const float* cw_w   = (const float*)d_in[5];
    const float* cw_b   = (const float*)d_in[6];
    const float* dh1w   = (const float*)d_in[7];
    const float* dh1b   = (const float*)d_in[8];
    const float* dh2w   = (const float*)d_in[9];
    const float* dh2b   = (const float*)d_in[10];
    const float* dw1w   = (const float*)d_in[11];
    const float* dw1b   = (const float*)d_in[12];
    const float* dw2w   = (const float*)d_in[13];
    const float* dw2b   = (const float*)d_in[14];
    float* out = (float*)d_out;

    // workspace layout (floats)
    float* ws    = (float*)d_ws;
    float* meanb = ws;                    // 8192
    float* scale = ws + 8192;             // 8192
    int*   sxp   = (int*)(ws + 16384);    // 8192
    int*   syp   = (int*)(ws + 24576);    // 8192
    float* chT   = ws + 32768;            // 65536
    float* cwT   = chT + 65536;           // 65536
    float* dh1T  = cwT + 65536;           // 16384
    float* dw1T  = dh1T + 16384;          // 16384
    float* dh2T  = dw1T + 16384;          // 65536
    float* dw2T  = dh2T + 65536;          // 65536

    transpose_weights<<<1152, 256, 0, stream>>>(ch_w, cw_w, dh1w, dw1w, dh2w, dw2w,
                                                chT, cwT, dh1T, dw1T, dh2T, dw2T);
    mean_kernel<<<NPLANES / 4, 256, 0, stream>>>(x, meanb);
    mlp_kernel<<<BATCH * 2, 256, 0, stream>>>(meanb, se_w1, se_w2, ch_b, cw_b,
                                              dh1b, dw1b, dh2b, dw2b,
                                              chT, cwT, dh1T, dw1T, dh2T, dw2T,
                                              scale, sxp, syp);
    apply_kernel<<<NPLANES, 256, 0, stream>>>(x, scale, sxp, syp, out);
}

// Round 6
// 293.606 us; speedup vs baseline: 1.1145x; 1.0167x over previous
//
#include <hip/hip_runtime.h>
#include <math.h>

// FeatGuide_BatchDrop: b=32, c=256, h=w=64, r_se=16, r_dy=4, K=2
// LAMBDAS={1,1,.5,.5}, INIT_V={1,0,0,0}, rh=3, rw=6
// sx=min(ceil(64*sig),61), sy=min(ceil(64*sig),58)

#define BATCH 32
#define CH 256
#define HW 64
#define PLANE (HW * HW)          // 4096
#define NPLANES (BATCH * CH)     // 8192

typedef float vf4 __attribute__((ext_vector_type(4)));

__device__ __forceinline__ float sigf(float x) { return 1.0f / (1.0f + expf(-x)); }

// ---------------------------------------------------------------------------
// Kernel M: fused {per-plane mean | weight transpose}.
// blocks [0,2048):  mean of planes 4*bid .. 4*bid+3 (one wave each)
// blocks [2048,3200): transpose slice of the 6 weight matrices
// ---------------------------------------------------------------------------
__global__ __launch_bounds__(256) void mean_transpose_kernel(
    const float* __restrict__ x, float* __restrict__ mean,
    const float* __restrict__ ch_w, const float* __restrict__ cw_w,
    const float* __restrict__ dh1,  const float* __restrict__ dw1,
    const float* __restrict__ dh2,  const float* __restrict__ dw2,
    float* __restrict__ chT, float* __restrict__ cwT,
    float* __restrict__ dh1T, float* __restrict__ dw1T,
    float* __restrict__ dh2T, float* __restrict__ dw2T)
{
    if (blockIdx.x < 2048) {
        int wid = threadIdx.x >> 6, lane = threadIdx.x & 63;
        int p = blockIdx.x * 4 + wid;
        const vf4* xp = (const vf4*)(x + (size_t)p * PLANE);
        float s0 = 0.f, s1 = 0.f;
#pragma unroll
        for (int k = 0; k < 16; k += 2) {
            vf4 v0 = xp[lane + 64 * k];
            vf4 v1 = xp[lane + 64 * (k + 1)];
            s0 += (v0.x + v0.y) + (v0.z + v0.w);
            s1 += (v1.x + v1.y) + (v1.z + v1.w);
        }
        float s = s0 + s1;
#pragma unroll
        for (int off = 32; off; off >>= 1) s += __shfl_xor(s, off, 64);
        if (lane == 0) mean[p] = s * (1.f / 4096.f);
        return;
    }
    int idx = (blockIdx.x - 2048) * 256 + threadIdx.x;
    if (idx < 65536) {                    // ch_w 256x256
        int r = idx >> 8, c = idx & 255;
        chT[c * 256 + r] = ch_w[idx];
    } else if (idx < 131072) {            // cw_w 256x256
        int i = idx - 65536; int r = i >> 8, c = i & 255;
        cwT[c * 256 + r] = cw_w[i];
    } else if (idx < 147456) {            // dh_fc1w 64x256
        int i = idx - 131072; int r = i >> 8, c = i & 255;
        dh1T[c * 64 + r] = dh1[i];
    } else if (idx < 163840) {            // dw_fc1w 64x256
        int i = idx - 147456; int r = i >> 8, c = i & 255;
        dw1T[c * 64 + r] = dw1[i];
    } else if (idx < 229376) {            // dh_fc2w 1024x64
        int i = idx - 163840; int r = i >> 6, c = i & 63;
        dh2T[c * 1024 + r] = dh2[i];
    } else if (idx < 294912) {            // dw_fc2w 1024x64
        int i = idx - 229376; int r = i >> 6, c = i & 63;
        dw2T[c * 1024 + r] = dw2[i];
    }
}

// ---------------------------------------------------------------------------
// Kernel B: one block per (batch, branch). Recomputes the tiny SE per block
// (redundant across the 2 branch blocks — cheaper than a launch + round-trip),
// then its dyrelu chain. branch 0 = h (sx), 1 = w (sy).
// ---------------------------------------------------------------------------
__global__ __launch_bounds__(256) void mlp_kernel(
    const float* __restrict__ mean,
    const float* __restrict__ se_w1, const float* __restrict__ se_w2,
    const float* __restrict__ ch_b,  const float* __restrict__ cw_b,
    const float* __restrict__ dh1b,  const float* __restrict__ dw1b,
    const float* __restrict__ dh2b,  const float* __restrict__ dw2b,
    const float* __restrict__ chT,   const float* __restrict__ cwT,
    const float* __restrict__ dh1T,  const float* __restrict__ dw1T,
    const float* __restrict__ dh2T,  const float* __restrict__ dw2T,
    float* __restrict__ scale, int* __restrict__ sx, int* __restrict__ sy)
{
    __shared__ float m_sh[256], part_sh[16][17], t1_sh[16];
    __shared__ float g_sh[256], v_sh[256], red_sh[4][64];
    __shared__ float th1_sh[64], th2_sh[1024];

    int b = blockIdx.x >> 1, br = blockIdx.x & 1;
    const float* cT  = br ? cwT  : chT;
    const float* cb  = br ? cw_b : ch_b;
    const float* f1T = br ? dw1T : dh1T;
    const float* f1b = br ? dw1b : dh1b;
    const float* f2T = br ? dw2T : dh2T;
    const float* f2b = br ? dw2b : dh2b;
    int*  so  = br ? sy : sx;
    float lim = br ? 58.f : 61.f;

    int t = threadIdx.x;
    m_sh[t] = mean[b * 256 + t];
    __syncthreads();

    // --- SE fc1: output o = t&15, partial part = t>>4 over 16 elements ---
    {
        int o = t & 15, part = t >> 4;
        const float* w = se_w1 + o * 256 + part * 16;
        const float* mm = m_sh + part * 16;
        float s = 0.f;
#pragma unroll
        for (int j = 0; j < 16; ++j) s = fmaf(mm[j], w[j], s);
        part_sh[o][part] = s;
    }
    __syncthreads();
    if (t < 16) {
        float a = 0.f;
#pragma unroll
        for (int p = 0; p < 16; ++p) a += part_sh[t][p];
        t1_sh[t] = fmaxf(a, 0.f);
    }
    __syncthreads();

    // --- SE fc2 + sigmoid; g = m*y ---
    {
        float acc = 0.f;
#pragma unroll
        for (int j = 0; j < 16; ++j) acc = fmaf(t1_sh[j], se_w2[t * 16 + j], acc);
        float y = sigf(acc);
        g_sh[t] = m_sh[t] * y;
        if (br == 0) scale[b * 256 + t] = y;
    }
    __syncthreads();

    // --- v = cT^T @ g + cb (coalesced column loads, g broadcast from LDS) ---
    float v = cb[t];
#pragma unroll 8
    for (int j = 0; j < 256; ++j) v = fmaf(g_sh[j], cT[j * 256 + t], v);
    v_sh[t] = v;
    __syncthreads();

    // --- dyrelu fc1: 64 outputs; 4 partials of 64 elems each ---
    {
        int o = t & 63, part = t >> 6;
        const float* vs = v_sh + part * 64;
        float s = 0.f;
#pragma unroll 8
        for (int j = 0; j < 64; ++j) s = fmaf(vs[j], f1T[(part * 64 + j) * 64 + o], s);
        red_sh[part][o] = s;
    }
    __syncthreads();
    if (t < 64)
        th1_sh[t] = fmaxf(red_sh[0][t] + red_sh[1][t] + red_sh[2][t] + red_sh[3][t] + f1b[t], 0.f);
    __syncthreads();

    // --- dyrelu fc2: 1024 outputs; thread t owns t, t+256, t+512, t+768 ---
    float a0 = 0, a1 = 0, a2 = 0, a3 = 0;
#pragma unroll 8
    for (int j = 0; j < 64; ++j) {
        float s1 = th1_sh[j];
        const float* p = f2T + j * 1024 + t;
        a0 = fmaf(s1, p[0],   a0);
        a1 = fmaf(s1, p[256], a1);
        a2 = fmaf(s1, p[512], a2);
        a3 = fmaf(s1, p[768], a3);
    }
    th2_sh[t      ] = a0 + f2b[t      ];
    th2_sh[t + 256] = a1 + f2b[t + 256];
    th2_sh[t + 512] = a2 + f2b[t + 512];
    th2_sh[t + 768] = a3 + f2b[t + 768];
    __syncthreads();

    // --- finalize channel t ---
    const float LAM[4] = {1.f, 1.f, 0.5f, 0.5f};
    const float INI[4] = {1.f, 0.f, 0.f, 0.f};
    float co[4];
#pragma unroll
    for (int i = 0; i < 4; ++i) {
        float th = 2.f * sigf(th2_sh[t * 4 + i]) - 1.f;
        co[i] = th * LAM[i] + INI[i];
    }
    float u = fmaxf(v * co[0] + co[2], v * co[1] + co[3]);
    so[b * 256 + t] = (int)fminf(ceilf(64.f * sigf(u)), lim);
}

// ---------------------------------------------------------------------------
// Kernel C: out = x * y[b,c], zeroing the 3x6 rectangle. 2 planes per block.
// Plain stores (NT stores caused post-timing divergence vs poison fills — R2).
// ---------------------------------------------------------------------------
__global__ __launch_bounds__(256) void apply_kernel(
    const float* __restrict__ x, const float* __restrict__ scale,
    const int* __restrict__ sx, const int* __restrict__ sy,
    float* __restrict__ out)
{
    int t = threadIdx.x;
#pragma unroll
    for (int pp = 0; pp < 2; ++pp) {
        int p = blockIdx.x * 2 + pp;
        float s = scale[p];
        int rx = sx[p], cy = sy[p];
        const vf4* xp = (const vf4*)(x + (size_t)p * PLANE);
        vf4* op = (vf4*)(out + (size_t)p * PLANE);
#pragma unroll
        for (int q = 0; q < 4; ++q) {
            int i4 = t + 256 * q;
            vf4 v = xp[i4];
            int row = i4 >> 4;              // (i4*4)/64
            int col0 = (i4 & 15) * 4;
            bool rin = (row >= rx) && (row < rx + 3);
            vf4 o;
            o.x = (rin && col0     >= cy && col0     < cy + 6) ? 0.f : v.x * s;
            o.y = (rin && col0 + 1 >= cy && col0 + 1 < cy + 6) ? 0.f : v.y * s;
            o.z = (rin && col0 + 2 >= cy && col0 + 2 < cy + 6) ? 0.f : v.z * s;
            o.w = (rin && col0 + 3 >= cy && col0 + 3 < cy + 6) ? 0.f : v.w * s;
            op[i4] = o;
        }
    }
}

// ---------------------------------------------------------------------------
extern "C" void kernel_launch(void* const* d_in, const int* in_sizes, int n_in,
                              void* d_out, int out_size, void* d_ws, size_t ws_size,
                              hipStream_t stream)
{
    const float* x      = (const float*)d_in[0];
    const float* se_w1  = (const float*)d_in[1];
    const float* se_w2  = (const float*)d_in[2];
    const float* ch_w   = (const float*)d_in[3];
    const float* ch_b   = (const float*)d_in[4];
    const float* cw_w   = (const float*)d_in[5];
    const float* cw_b   = (const float*)d_in[6];
    const float* dh1w   = (const float*)d_in[7];
    const float* dh1b   = (const float*)d_in[8];
    const float* dh2w   = (const float*)d_in[9];
    const float* dh2b   = (const float*)d_in[10];
    const float* dw1w   = (const float*)d_in[11];
    const float* dw1b   = (const float*)d_in[12];
    const float* dw2w   = (const float*)d_in[13];
    const float* dw2b   = (const float*)d_in[14];
    float* out = (float*)d_out;

    // workspace layout (floats)
    float* ws    = (float*)d_ws;
    float* meanb = ws;                    // 8192
    float* scale = ws + 8192;             // 8192
    int*   sxp   = (int*)(ws + 16384);    // 8192
    int*   syp   = (int*)(ws + 24576);    // 8192
    float* chT   = ws + 32768;            // 65536
    float* cwT   = chT + 65536;           // 65536
    float* dh1T  = cwT + 65536;           // 16384
    float* dw1T  = dh1T + 16384;          // 16384
    float* dh2T  = dw1T + 16384;          // 65536
    float* dw2T  = dh2T + 65536;          // 65536

    mean_transpose_kernel<<<3200, 256, 0, stream>>>(
        x, meanb, ch_w, cw_w, dh1w, dw1w, dh2w, dw2w,
        chT, cwT, dh1T, dw1T, dh2T, dw2T);
    mlp_kernel<<<BATCH * 2, 256, 0, stream>>>(meanb, se_w1, se_w2, ch_b, cw_b,
                                              dh1b, dw1b, dh2b, dw2b,
                                              chT, cwT, dh1T, dw1T, dh2T, dw2T,
                                              scale, sxp, syp);
    apply_kernel<<<NPLANES / 2, 256, 0, stream>>>(x, scale, sxp, syp, out);
}